// Round 9
// baseline (3245.085 us; speedup 1.0000x reference)
//
#include <hip/hip_runtime.h>
#include <math.h>

// ---------------- problem constants ----------------
constexpr int Bc = 32, Cch = 3, Hh = 224, Ww = 224, Pp = 16;
constexpr int Dd = 768, NH = 12, DHd = 64, INNERc = 768;
constexpr int DEPTHc = 12, NCLS = 1000;
constexpr int NPc = 196, Nn = 197, PD = 768;
constexpr float EPSf = 1e-5f;

typedef _Float16 half_t;
typedef __attribute__((ext_vector_type(8))) _Float16 half8;
typedef __attribute__((ext_vector_type(4))) float f32x4;
typedef __attribute__((ext_vector_type(4))) unsigned int uint32x4;

// ---------------- reduction helpers ----------------
__device__ __forceinline__ float wave_red_sum(float v) {
#pragma unroll
    for (int m = 32; m; m >>= 1) v += __shfl_xor(v, m);
    return v;
}

__device__ __forceinline__ void block_red2(float& s, float& s2, float* red) {
    s = wave_red_sum(s);
    s2 = wave_red_sum(s2);
    int wid = threadIdx.x >> 6, lane = threadIdx.x & 63;
    if (lane == 0) { red[wid] = s; red[4 + wid] = s2; }
    __syncthreads();
    s = red[0] + red[1] + red[2] + red[3];
    s2 = red[4] + red[5] + red[6] + red[7];
}

// ---------------- patchify + patch LN -> f16 ----------------
__global__ __launch_bounds__(256) void k_patch_ln(
        const float* __restrict__ img, const float* __restrict__ g,
        const float* __restrict__ bb, half_t* __restrict__ out) {
    int pid = blockIdx.x;
    int b = pid / NPc, n = pid % NPc;
    int ph = n / 14, pw = n % 14;
    int t = threadIdx.x;
    __shared__ float red[8];
    float v[3];
#pragma unroll
    for (int i = 0; i < 3; i++) {
        int d = t + i * 256;
        int c = d % 3, q = (d / 3) & 15, p = d / 48;
        v[i] = img[((long)(b * Cch + c) * Hh + ph * Pp + p) * Ww + pw * Pp + q];
    }
    float s = v[0] + v[1] + v[2];
    float s2 = v[0] * v[0] + v[1] * v[1] + v[2] * v[2];
    block_red2(s, s2, red);
    float mu = s * (1.f / PD);
    float var = s2 * (1.f / PD) - mu * mu;
    float r = rsqrtf(var + EPSf);
#pragma unroll
    for (int i = 0; i < 3; i++) {
        int d = t + i * 256;
        out[(long)pid * PD + d] = (half_t)((v[i] - mu) * r * g[d] + bb[d]);
    }
}

// ---------------- row LayerNorm (768 wide), templated output ----------------
template <typename T>
__global__ __launch_bounds__(256) void k_ln(
        const float* __restrict__ in, const float* __restrict__ g,
        const float* __restrict__ bb, T* __restrict__ out,
        long in_stride, long out_stride) {
    long row = blockIdx.x;
    const float* ip = in + row * in_stride;
    T* op = out + row * out_stride;
    int t = threadIdx.x;
    __shared__ float red[8];
    float v[3];
#pragma unroll
    for (int i = 0; i < 3; i++) v[i] = ip[t + i * 256];
    float s = v[0] + v[1] + v[2];
    float s2 = v[0] * v[0] + v[1] * v[1] + v[2] * v[2];
    block_red2(s, s2, red);
    float mu = s * (1.f / Dd);
    float var = s2 * (1.f / Dd) - mu * mu;
    float r = rsqrtf(var + EPSf);
#pragma unroll
    for (int i = 0; i < 3; i++) {
        int d = t + i * 256;
        op[d] = (T)((v[i] - mu) * r * g[d] + bb[d]);
    }
}

// ---------------- embed assemble: LN(tmp)+pos, cls+pos ----------------
__global__ __launch_bounds__(256) void k_embed(
        const float* __restrict__ tmp, const float* __restrict__ cls,
        const float* __restrict__ pos, const float* __restrict__ g,
        const float* __restrict__ bb, float* __restrict__ x) {
    int pid = blockIdx.x;
    int b = pid / Nn, n = pid % Nn;
    int t = threadIdx.x;
    float* xp = x + (long)pid * Dd;
    if (n == 0) {
#pragma unroll
        for (int i = 0; i < 3; i++) {
            int d = t + i * 256;
            xp[d] = cls[d] + pos[d];
        }
        return;
    }
    const float* ip = tmp + (long)(b * NPc + n - 1) * Dd;
    __shared__ float red[8];
    float v[3];
#pragma unroll
    for (int i = 0; i < 3; i++) v[i] = ip[t + i * 256];
    float s = v[0] + v[1] + v[2];
    float s2 = v[0] * v[0] + v[1] * v[1] + v[2] * v[2];
    block_red2(s, s2, red);
    float mu = s * (1.f / Dd);
    float var = s2 * (1.f / Dd) - mu * mu;
    float r = rsqrtf(var + EPSf);
#pragma unroll
    for (int i = 0; i < 3; i++) {
        int d = t + i * 256;
        xp[d] = (v[i] - mu) * r * g[d] + bb[d] + pos[(long)n * Dd + d];
    }
}

// ---------------- weight prep: fp32 W[K][N] -> f16 Wt[N][K] ----------------
__global__ __launch_bounds__(256) void k_wprep(
        const float* __restrict__ W, half_t* __restrict__ Wt, int K, int N) {
    W += (long)blockIdx.z * K * N;
    Wt += (long)blockIdx.z * K * N;
    __shared__ float tile[32][33];
    int n = blockIdx.x * 32 + threadIdx.x;
    int k0 = blockIdx.y * 32;
#pragma unroll
    for (int i = 0; i < 4; i++)
        tile[threadIdx.y + i * 8][threadIdx.x] = W[(long)(k0 + threadIdx.y + i * 8) * N + n];
    __syncthreads();
    int kk = k0 + threadIdx.x;
#pragma unroll
    for (int i = 0; i < 4; i++)
        Wt[(long)(blockIdx.x * 32 + threadIdx.y + i * 8) * K + kk] =
            (half_t)tile[threadIdx.x][threadIdx.y + i * 8];
}

// ---------------- head weight prep: fp32 [768][1000] -> f16 [1024][768] (pad 0) --------
__global__ __launch_bounds__(256) void k_wprep_head(
        const float* __restrict__ W, half_t* __restrict__ Wt) {
    __shared__ float tile[32][33];
    int n = blockIdx.x * 32 + threadIdx.x;
    int k0 = blockIdx.y * 32;
#pragma unroll
    for (int i = 0; i < 4; i++)
        tile[threadIdx.y + i * 8][threadIdx.x] =
            (n < NCLS) ? W[(long)(k0 + threadIdx.y + i * 8) * NCLS + n] : 0.f;
    __syncthreads();
    int kk = k0 + threadIdx.x;
#pragma unroll
    for (int i = 0; i < 4; i++)
        Wt[(long)(blockIdx.x * 32 + threadIdx.y + i * 8) * Dd + kk] =
            (half_t)tile[threadIdx.x][threadIdx.y + i * 8];
}

// ---------------- head GEMM: one thread per (row,col), f16 dot ----------------
__global__ __launch_bounds__(256) void k_head(
        const half_t* __restrict__ Ah, const half_t* __restrict__ Wh,
        const float* __restrict__ bias, float* __restrict__ out) {
    int idx = blockIdx.x * 256 + threadIdx.x;
    int row = idx >> 10, col = idx & 1023;
    if (col >= NCLS) return;
    const half_t* ap = Ah + (long)row * Dd;
    const half_t* wp = Wh + (long)col * Dd;
    float acc = 0.f;
#pragma unroll
    for (int k = 0; k < 96; k++) {
        half8 a = *(const half8*)&ap[k * 8];
        half8 w = *(const half8*)&wp[k * 8];
#pragma unroll
        for (int u = 0; u < 8; u++) acc += (float)a[u] * (float)w[u];
    }
    out[(long)row * NCLS + col] = acc + bias[col];
}

// ---------------- LN+pack helper: 8 fp32 -> LN -> half8 ----------------
__device__ __forceinline__ uint32x4 ln_pack(const float* xp, float mu, float rs,
                                            f32x4 g0, f32x4 g1, f32x4 b0, f32x4 b1) {
    f32x4 v0 = *(const f32x4*)xp;
    f32x4 v1 = *(const f32x4*)(xp + 4);
    union { uint32x4 u; half8 h; } t;
#pragma unroll
    for (int u2 = 0; u2 < 4; u2++) {
        t.h[u2]     = (half_t)((v0[u2] - mu) * rs * g0[u2] + b0[u2]);
        t.h[u2 + 4] = (half_t)((v1[u2] - mu) * rs * g1[u2] + b1[u2]);
    }
    return t.u;
}

// ---------------- f16 MFMA GEMM ----------------
// LNF=1: A is fp32 x, LayerNorm (lng,lnb) fused into A-staging.
// OMODE=1 (qkv): C=q, C1=k head-major [b,h,n,64]; V third (n0>=1536) written
//   directly from acc, TRANSPOSED+padded into Vt [b,h,64,224].
__device__ __forceinline__ half8 lds_frag(const uint32x4 (*L)[8], int row, int slot) {
    union { uint32x4 u; half8 h; } t;
    t.u = L[row][slot];
    return t.h;
}

template <int HASB, int HASR, typename CT, int OMODE, int LNF>
__global__ __launch_bounds__(256, 2) void k_hgemm(
        const void* __restrict__ Av, const half_t* __restrict__ Bt,
        const float* __restrict__ bias, const float* __restrict__ res,
        const float* __restrict__ lng, const float* __restrict__ lnb,
        CT* __restrict__ C, CT* __restrict__ C1, half_t* __restrict__ Vt,
        int M, int N, int K) {
    __shared__ uint32x4 smem[2176];
    __shared__ float murs[128][2];
    uint32x4 (*As)[8] = (uint32x4(*)[8])smem;
    uint32x4 (*Bs)[8] = (uint32x4(*)[8])(smem + 1024);
    const half_t* Ah = (const half_t*)Av;
    const float*  Af = (const float*)Av;
    const int tid = threadIdx.x;
    const int nwg = gridDim.x;
    const int q8 = nwg >> 3, r8 = nwg & 7;
    const int xc = blockIdx.x & 7, oo = blockIdx.x >> 3;
    const int tile = (xc < r8 ? xc * (q8 + 1) : r8 * (q8 + 1) + (xc - r8) * q8) + oo;
    const int gx = N >> 7;
    const int n0 = (tile % gx) * 128, m0 = (tile / gx) * 128;
    const int lane = tid & 63, w = tid >> 6;
    const int wrr = (w >> 1) * 64, wcc = (w & 1) * 64;
    const int lrow = lane & 15, lgrp = lane >> 4;

    // ---- LN prologue: mean/rsqrt-var for this block's 128 A-rows ----
    if constexpr (LNF) {
        int rowp = tid >> 1, hf = tid & 1;
        const float* xr = Af + (long)min(m0 + rowp, M - 1) * K + hf * (K / 2);
        float s = 0.f, s2 = 0.f;
        for (int k = 0; k < K / 2; k += 8) {
            f32x4 v0 = *(const f32x4*)(xr + k);
            f32x4 v1 = *(const f32x4*)(xr + k + 4);
#pragma unroll
            for (int u = 0; u < 4; u++) {
                s += v0[u] + v1[u];
                s2 += v0[u] * v0[u] + v1[u] * v1[u];
            }
        }
        s += __shfl_xor(s, 1);
        s2 += __shfl_xor(s2, 1);
        if (hf == 0) {
            float mu = s * (1.f / K);
            float var = s2 * (1.f / K) - mu * mu;
            murs[rowp][0] = mu;
            murs[rowp][1] = rsqrtf(var + EPSf);
        }
        __syncthreads();
    }

    int lm[4], sw[4];
    long gA[4], gB[4];
    const int cb = (tid & 7) * 8;
#pragma unroll
    for (int c = 0; c < 4; ++c) {
        lm[c] = c * 32 + (tid >> 3);
        sw[c] = (tid & 7) ^ (lm[c] & 7);
        int ma = m0 + lm[c];
        if (ma > M - 1) ma = M - 1;
        gA[c] = (long)ma * K + cb;
        gB[c] = (long)(n0 + lm[c]) * K + cb;
    }
    float muc[4], rsc[4];
    if constexpr (LNF) {
#pragma unroll
        for (int c = 0; c < 4; ++c) { muc[c] = murs[lm[c]][0]; rsc[c] = murs[lm[c]][1]; }
    }

    f32x4 acc[4][4] = {};
    uint32x4 ha[4], rb[4];
    f32x4 gv0, gv1, bv0, bv1;
    if constexpr (LNF) {
        gv0 = *(const f32x4*)(lng + cb);  gv1 = *(const f32x4*)(lng + cb + 4);
        bv0 = *(const f32x4*)(lnb + cb);  bv1 = *(const f32x4*)(lnb + cb + 4);
    }
#pragma unroll
    for (int c = 0; c < 4; ++c) {
        if constexpr (LNF)
            ha[c] = ln_pack(Af + gA[c], muc[c], rsc[c], gv0, gv1, bv0, bv1);
        else
            ha[c] = *(const uint32x4*)(Ah + gA[c]);
        rb[c] = *(const uint32x4*)(Bt + gB[c]);
    }
#pragma unroll
    for (int c = 0; c < 4; ++c) { As[lm[c]][sw[c]] = ha[c]; Bs[lm[c]][sw[c]] = rb[c]; }
    __syncthreads();

    const int nst = K >> 6;
    for (int t = 0; t < nst; ++t) {
        if (t + 1 < nst) {
            const int k0 = (t + 1) << 6;
            if constexpr (LNF) {
                gv0 = *(const f32x4*)(lng + k0 + cb);  gv1 = *(const f32x4*)(lng + k0 + cb + 4);
                bv0 = *(const f32x4*)(lnb + k0 + cb);  bv1 = *(const f32x4*)(lnb + k0 + cb + 4);
            }
#pragma unroll
            for (int c = 0; c < 4; ++c) {
                if constexpr (LNF)
                    ha[c] = ln_pack(Af + gA[c] + k0, muc[c], rsc[c], gv0, gv1, bv0, bv1);
                else
                    ha[c] = *(const uint32x4*)(Ah + gA[c] + k0);
                rb[c] = *(const uint32x4*)(Bt + gB[c] + k0);
            }
        }
#pragma unroll
        for (int kh = 0; kh < 2; ++kh) {
            half8 af[4], bf[4];
#pragma unroll
            for (int i2 = 0; i2 < 4; ++i2) {
                int m = wrr + i2 * 16 + lrow;
                af[i2] = lds_frag(As, m, (kh * 4 + lgrp) ^ (m & 7));
                int n = wcc + i2 * 16 + lrow;
                bf[i2] = lds_frag(Bs, n, (kh * 4 + lgrp) ^ (n & 7));
            }
#pragma unroll
            for (int i2 = 0; i2 < 4; ++i2)
#pragma unroll
                for (int j2 = 0; j2 < 4; ++j2)
                    acc[i2][j2] = __builtin_amdgcn_mfma_f32_16x16x32_f16(af[i2], bf[j2], acc[i2][j2], 0, 0, 0);
        }
        if (t + 1 < nst) {
            __syncthreads();
#pragma unroll
            for (int c = 0; c < 4; ++c) { As[lm[c]][sw[c]] = ha[c]; Bs[lm[c]][sw[c]] = rb[c]; }
            __syncthreads();
        }
    }

    if constexpr (sizeof(CT) == 2) {
        if constexpr (OMODE == 1) {
            if (n0 >= 1536) {
                // V third: write transposed+padded straight from acc -> Vt[b,h,d,nn]
#pragma unroll
                for (int i2 = 0; i2 < 4; ++i2)
#pragma unroll
                    for (int j2 = 0; j2 < 4; ++j2) {
                        int colc = wcc + j2 * 16 + lrow;
                        int rem = n0 + colc - 1536;
                        int h = rem >> 6, d = rem & 63;
#pragma unroll
                        for (int q = 0; q < 4; ++q) {
                            int token = m0 + wrr + i2 * 16 + lgrp * 4 + q;
                            if (token < M) {
                                int b = token / Nn, nn = token - b * Nn;
                                __builtin_nontemporal_store((half_t)acc[i2][j2][q],
                                    Vt + ((long)(b * NH + h) * 64 + d) * 224 + nn);
                            }
                        }
                    }
                return;
            }
        }
        __syncthreads();
        half_t* Cs = (half_t*)smem;
#pragma unroll
        for (int i2 = 0; i2 < 4; ++i2)
#pragma unroll
            for (int j2 = 0; j2 < 4; ++j2) {
                int colc = wcc + j2 * 16 + lrow;
                float bv = HASB ? bias[n0 + colc] : 0.f;
#pragma unroll
                for (int q = 0; q < 4; ++q) {
                    int r = wrr + i2 * 16 + lgrp * 4 + q;
                    Cs[r * 136 + colc] = (half_t)(acc[i2][j2][q] + bv);
                }
            }
        __syncthreads();
#pragma unroll
        for (int it = 0; it < 8; ++it) {
            int idx = tid + it * 256;
            int row = idx >> 4, cu = idx & 15;
            int token = m0 + row;
            if (token < M) {
                uint32x4 val = *(const uint32x4*)(Cs + row * 136 + cu * 8);
                if constexpr (OMODE == 1) {
                    int gc = n0 + cu * 8;
                    int which = gc >= 768 ? 1 : 0;
                    int rem = gc - which * 768;
                    int h = rem >> 6, d = rem & 63;
                    int b = token / Nn, nn = token - b * Nn;
                    CT* dst = (which == 0 ? C : C1);
                    __builtin_nontemporal_store(val,
                        (uint32x4*)(dst + (((long)(b * NH + h) * Nn + nn) << 6) + d));
                } else {
                    __builtin_nontemporal_store(val,
                        (uint32x4*)(C + (long)token * N + n0 + cu * 8));
                }
            }
        }
    } else {
#pragma unroll
        for (int i2 = 0; i2 < 4; ++i2)
#pragma unroll
            for (int j2 = 0; j2 < 4; ++j2) {
                int colc = n0 + wcc + j2 * 16 + lrow;
                float bv = HASB ? bias[colc] : 0.f;
#pragma unroll
                for (int q = 0; q < 4; ++q) {
                    int r = m0 + wrr + i2 * 16 + lgrp * 4 + q;
                    if (r < M) {
                        float v = acc[i2][j2][q] + bv;
                        if (HASR) v += res[(long)r * N + colc];
                        __builtin_nontemporal_store(v, &C[(long)r * N + colc]);
                    }
                }
            }
    }
}

// ---------------- attention stats: cross-head mu & rsqrt(var), fragment layout --------
__global__ __launch_bounds__(256) void k_stats(
        const half_t* __restrict__ qh, const half_t* __restrict__ kh,
        f32x4* __restrict__ muT, f32x4* __restrict__ rsT) {
    const int blk = (blockIdx.x & 7) * 169 + (blockIdx.x >> 3);   // 1352 = 8*169
    const int w = threadIdx.x >> 6, lane = threadIdx.x & 63;
    const int task = blk * 4 + w;                                  // 5408 = 32*169
    const int b = task / 169, r = task % 169;
    const int it = r / 13, jt = r % 13;
    const int lrow = lane & 15, lg = lane >> 4;
    const int i0 = it * 16, j0 = jt * 16;
    const int arow = min(i0 + lrow, Nn - 1);
    const int jr = min(j0 + lrow, Nn - 1);
    const int hbase = b * NH;

    float sv[4] = {}, sq[4] = {};
#pragma unroll
    for (int h = 0; h < NH; h++) {
        const half_t* Qp = qh + ((long)(hbase + h) * Nn) * 64;
        const half_t* Kp = kh + ((long)(hbase + h) * Nn) * 64;
        half8 af0 = *(const half8*)&Qp[(long)arow * 64 + lg * 8];
        half8 af1 = *(const half8*)&Qp[(long)arow * 64 + 32 + lg * 8];
        half8 bf0 = *(const half8*)&Kp[(long)jr * 64 + lg * 8];
        half8 bf1 = *(const half8*)&Kp[(long)jr * 64 + 32 + lg * 8];
        f32x4 acc = {};
        acc = __builtin_amdgcn_mfma_f32_16x16x32_f16(af0, bf0, acc, 0, 0, 0);
        acc = __builtin_amdgcn_mfma_f32_16x16x32_f16(af1, bf1, acc, 0, 0, 0);
#pragma unroll
        for (int q = 0; q < 4; q++) { sv[q] += acc[q]; sq[q] += acc[q] * acc[q]; }
    }
    f32x4 muv, rsv;
#pragma unroll
    for (int q = 0; q < 4; q++) {
        float mu = sv[q] * (1.f / NH);
        float var = (sq[q] - sv[q] * mu) * (1.f / (NH - 1));
        muv[q] = mu;
        rsv[q] = rsqrtf(var);
    }
    long idx = ((long)(b * 13 + it) * 13 + jt) * 64 + lane;
    muT[idx] = muv;
    rsT[idx] = rsv;
}

// ---------------- attention per head: S recompute + z-score + softmax + PV ----------------
__global__ __launch_bounds__(64) void k_attn2(
        const half_t* __restrict__ qh, const half_t* __restrict__ kh,
        const half_t* __restrict__ vt, const f32x4* __restrict__ muT,
        const f32x4* __restrict__ rsT, half_t* __restrict__ o) {
    __shared__ half_t PB[16][232];
    const int tile = (blockIdx.x & 7) * 624 + (blockIdx.x >> 3);  // 4992 = 8*624
    const int bh = tile / 13, it = tile % 13;
    const int b = bh / NH, h = bh % NH;
    const int i0 = it * 16;
    const int lane = threadIdx.x;
    const int lrow = lane & 15, lg = lane >> 4;
    const int arow = min(i0 + lrow, Nn - 1);

    for (int idx = lane; idx < 16 * 12; idx += 64) {
        int rr = idx / 12, u = idx % 12;
        *(unsigned int*)&PB[rr][208 + u * 2] = 0u;
    }

    const half_t* Qp = qh + ((long)bh * Nn) * 64;
    const half_t* Kp = kh + ((long)bh * Nn) * 64;
    half8 af0 = *(const half8*)&Qp[(long)arow * 64 + lg * 8];
    half8 af1 = *(const half8*)&Qp[(long)arow * 64 + 32 + lg * 8];
    const f32x4* muB = muT + ((long)(b * 13 + it) * 13) * 64 + lane;
    const f32x4* rsB = rsT + ((long)(b * 13 + it) * 13) * 64 + lane;

    float ez[13][4];
    float mx[4] = {-1e30f, -1e30f, -1e30f, -1e30f};
#pragma unroll
    for (int jt = 0; jt < 13; jt++) {
        int jr = min(jt * 16 + lrow, Nn - 1);
        half8 bf0 = *(const half8*)&Kp[(long)jr * 64 + lg * 8];
        half8 bf1 = *(const half8*)&Kp[(long)jr * 64 + 32 + lg * 8];
        f32x4 acc = {};
        acc = __builtin_amdgcn_mfma_f32_16x16x32_f16(af0, bf0, acc, 0, 0, 0);
        acc = __builtin_amdgcn_mfma_f32_16x16x32_f16(af1, bf1, acc, 0, 0, 0);
        f32x4 mu4 = muB[jt * 64];
        f32x4 rs4 = rsB[jt * 64];
        bool joob = (jt * 16 + lrow) > Nn - 1;
#pragma unroll
        for (int q = 0; q < 4; q++) {
            float z = (acc[q] - mu4[q]) * rs4[q];
            if (joob) z = -1e30f;
            ez[jt][q] = z;
            mx[q] = fmaxf(mx[q], z);
        }
    }
#pragma unroll
    for (int st = 1; st <= 8; st <<= 1)
#pragma unroll
        for (int q = 0; q < 4; q++) mx[q] = fmaxf(mx[q], __shfl_xor(mx[q], st));
    float sm[4] = {0.f, 0.f, 0.f, 0.f};
#pragma unroll
    for (int jt = 0; jt < 13; jt++)
#pragma unroll
        for (int q = 0; q < 4; q++) {
            float e = __expf(ez[jt][q] - mx[q]);
            ez[jt][q] = e;
            sm[q] += e;
        }
#pragma unroll
    for (int st = 1; st <= 8; st <<= 1)
#pragma unroll
        for (int q = 0; q < 4; q++) sm[q] += __shfl_xor(sm[q], st);
    float inv[4];
#pragma unroll
    for (int q = 0; q < 4; q++) inv[q] = 1.f / sm[q];
#pragma unroll
    for (int jt = 0; jt < 13; jt++)
#pragma unroll
        for (int q = 0; q < 4; q++)
            PB[lg * 4 + q][jt * 16 + lrow] = (half_t)(ez[jt][q] * inv[q]);
    __syncthreads();

    const half_t* Vtp = vt + ((long)bh * 64) * 224;
#pragma unroll
    for (int dt = 0; dt < 4; dt++) {
        f32x4 oacc = {};
#pragma unroll
        for (int kt = 0; kt < 7; kt++) {
            half8 pa = *(const half8*)&PB[lrow][kt * 32 + lg * 8];
            half8 vb = *(const half8*)&Vtp[(long)(dt * 16 + lrow) * 224 + kt * 32 + lg * 8];
            oacc = __builtin_amdgcn_mfma_f32_16x16x32_f16(pa, vb, oacc, 0, 0, 0);
        }
#pragma unroll
        for (int q = 0; q < 4; q++) {
            int i = i0 + lg * 4 + q;
            if (i < Nn)
                o[((long)(b * Nn) + i) * INNERc + h * 64 + dt * 16 + lrow] = (half_t)oacc[q];
        }
    }
}

// ---------------- host launcher ----------------
extern "C" void kernel_launch(void* const* d_in, const int* in_sizes, int n_in,
                              void* d_out, int out_size, void* d_ws, size_t ws_size,
                              hipStream_t stream) {
    const float* img     = (const float*)d_in[0];
    const float* patch_g = (const float*)d_in[2];
    const float* patch_b = (const float*)d_in[3];
    const float* W_patch = (const float*)d_in[4];
    const float* b_patch = (const float*)d_in[5];
    const float* emb_g   = (const float*)d_in[6];
    const float* emb_b   = (const float*)d_in[7];
    const float* pos     = (const float*)d_in[8];
    const float* cls     = (const float*)d_in[9];
    const float* ln_g    = (const float*)d_in[10];
    const float* ln_b    = (const float*)d_in[11];
    const float* W_qkv   = (const float*)d_in[12];
    const float* W_out   = (const float*)d_in[13];
    const float* b_out   = (const float*)d_in[14];
    const float* fin_g   = (const float*)d_in[15];
    const float* fin_b   = (const float*)d_in[16];
    const float* W_head  = (const float*)d_in[17];
    const float* b_head  = (const float*)d_in[18];
    float* out = (float*)d_out;

    const long SZ_XD  = (long)Bc * Nn * Dd;            // 4,841,472
    const long SZ_HD  = (long)Bc * NH * Nn * DHd;      // 4,841,472
    const long SZ_VT  = (long)Bc * NH * 64 * 224;      // 5,505,024
    const long SZ_TMP = (long)Bc * NPc * Dd;
    const long SZ_MU  = (long)Bc * 169 * 256 + 1024;   // fragment-layout stats

    float* x    = (float*)d_ws;
    float* tmp  = x + SZ_XD;
    float* muG  = tmp + SZ_TMP;
    float* rsG  = muG + SZ_MU;
    half_t* xh       = (half_t*)(rsG + SZ_MU);
    half_t* qhb      = xh + SZ_XD;
    half_t* khb      = qhb + SZ_HD;
    half_t* vtb      = khb + SZ_HD;
    half_t* clsh     = vtb + SZ_VT;                         // 32x768 f16
    half_t* wh_head  = clsh + 32 * Dd;                      // 1024x768 f16
    half_t* wt_patch = wh_head + 1024 * Dd;
    half_t* wt_qkv   = wt_patch + (long)Dd * Dd;
    half_t* wt_out   = wt_qkv + (long)DEPTHc * 3 * INNERc * Dd;

    // ---- weight prep ----
    hipLaunchKernelGGL(k_wprep, dim3(Dd / 32, Dd / 32, 1), dim3(32, 8), 0, stream,
                       W_patch, wt_patch, Dd, Dd);
    hipLaunchKernelGGL(k_wprep, dim3(3 * INNERc / 32, Dd / 32, DEPTHc), dim3(32, 8), 0, stream,
                       W_qkv, wt_qkv, Dd, 3 * INNERc);
    hipLaunchKernelGGL(k_wprep, dim3(Dd / 32, Dd / 32, DEPTHc), dim3(32, 8), 0, stream,
                       W_out, wt_out, Dd, Dd);
    hipLaunchKernelGGL(k_wprep_head, dim3(32, 24), dim3(32, 8), 0, stream,
                       W_head, wh_head);

    // 1. patchify + patch LN -> xh (f16)
    hipLaunchKernelGGL(k_patch_ln, dim3(Bc * NPc), dim3(256), 0, stream,
                       img, patch_g, patch_b, xh);
    // 2. patch GEMM (+b_patch) -> tmp fp32
    hipLaunchKernelGGL((k_hgemm<1, 0, float, 0, 0>), dim3(6 * 49), dim3(256), 0, stream,
                       xh, wt_patch, b_patch, nullptr, nullptr, nullptr,
                       tmp, nullptr, nullptr, Bc * NPc, Dd, Dd);
    // 3. emb LN + cls concat + pos add -> x
    hipLaunchKernelGGL(k_embed, dim3(Bc * Nn), dim3(256), 0, stream,
                       tmp, cls, pos, emb_g, emb_b, x);

    const int Mrows = Bc * Nn;  // 6304
    for (int l = 0; l < DEPTHc; l++) {
        const float* g  = ln_g + (long)l * Dd;
        const float* bb = ln_b + (long)l * Dd;
        const half_t* Wq = wt_qkv + (long)l * 3 * INNERc * Dd;
        const half_t* Wo = wt_out + (long)l * Dd * Dd;
        const float* bo = b_out + (long)l * Dd;
        // fused LN + qkv GEMM; V written transposed directly
        hipLaunchKernelGGL((k_hgemm<0, 0, half_t, 1, 1>), dim3(18 * 50), dim3(256), 0, stream,
                           x, Wq, nullptr, nullptr, g, bb,
                           qhb, khb, vtb, Mrows, 3 * INNERc, Dd);
        hipLaunchKernelGGL(k_stats, dim3(1352), dim3(256), 0, stream,
                           qhb, khb, (f32x4*)muG, (f32x4*)rsG);
        hipLaunchKernelGGL(k_attn2, dim3(4992), dim3(64), 0, stream,
                           qhb, khb, vtb, (const f32x4*)muG, (const f32x4*)rsG, xh);
        hipLaunchKernelGGL((k_hgemm<1, 1, float, 0, 0>), dim3(6 * 50), dim3(256), 0, stream,
                           xh, Wo, bo, x, nullptr, nullptr,
                           x, nullptr, nullptr, Mrows, Dd, Dd);
    }
    // final LN (cls rows only) -> clsh f16
    hipLaunchKernelGGL((k_ln<half_t>), dim3(Bc), dim3(256), 0, stream,
                       x, fin_g, fin_b, clsh, (long)Nn * Dd, (long)Dd);
    // head GEMM: f16 dot per (row,col)
    hipLaunchKernelGGL(k_head, dim3(128), dim3(256), 0, stream,
                       clsh, wh_head, b_head, out);
}

// Round 10
// 2555.116 us; speedup vs baseline: 1.2700x; 1.2700x over previous
//
#include <hip/hip_runtime.h>
#include <math.h>

// ---------------- problem constants ----------------
constexpr int Bc = 32, Cch = 3, Hh = 224, Ww = 224, Pp = 16;
constexpr int Dd = 768, NH = 12, DHd = 64, INNERc = 768;
constexpr int DEPTHc = 12, NCLS = 1000;
constexpr int NPc = 196, Nn = 197, PD = 768;
constexpr float EPSf = 1e-5f;

typedef _Float16 half_t;
typedef __attribute__((ext_vector_type(8))) _Float16 half8;
typedef __attribute__((ext_vector_type(4))) float f32x4;
typedef __attribute__((ext_vector_type(4))) unsigned int uint32x4;

// ---------------- reduction helpers ----------------
__device__ __forceinline__ float wave_red_sum(float v) {
#pragma unroll
    for (int m = 32; m; m >>= 1) v += __shfl_xor(v, m);
    return v;
}

__device__ __forceinline__ void block_red2(float& s, float& s2, float* red) {
    s = wave_red_sum(s);
    s2 = wave_red_sum(s2);
    int wid = threadIdx.x >> 6, lane = threadIdx.x & 63;
    if (lane == 0) { red[wid] = s; red[4 + wid] = s2; }
    __syncthreads();
    s = red[0] + red[1] + red[2] + red[3];
    s2 = red[4] + red[5] + red[6] + red[7];
}

// ---------------- patchify + patch LN -> f16 ----------------
__global__ __launch_bounds__(256) void k_patch_ln(
        const float* __restrict__ img, const float* __restrict__ g,
        const float* __restrict__ bb, half_t* __restrict__ out) {
    int pid = blockIdx.x;
    int b = pid / NPc, n = pid % NPc;
    int ph = n / 14, pw = n % 14;
    int t = threadIdx.x;
    __shared__ float red[8];
    float v[3];
#pragma unroll
    for (int i = 0; i < 3; i++) {
        int d = t + i * 256;
        int c = d % 3, q = (d / 3) & 15, p = d / 48;
        v[i] = img[((long)(b * Cch + c) * Hh + ph * Pp + p) * Ww + pw * Pp + q];
    }
    float s = v[0] + v[1] + v[2];
    float s2 = v[0] * v[0] + v[1] * v[1] + v[2] * v[2];
    block_red2(s, s2, red);
    float mu = s * (1.f / PD);
    float var = s2 * (1.f / PD) - mu * mu;
    float r = rsqrtf(var + EPSf);
#pragma unroll
    for (int i = 0; i < 3; i++) {
        int d = t + i * 256;
        out[(long)pid * PD + d] = (half_t)((v[i] - mu) * r * g[d] + bb[d]);
    }
}

// ---------------- row LayerNorm (768 wide), templated output ----------------
template <typename T>
__global__ __launch_bounds__(256) void k_ln(
        const float* __restrict__ in, const float* __restrict__ g,
        const float* __restrict__ bb, T* __restrict__ out,
        long in_stride, long out_stride) {
    long row = blockIdx.x;
    const float* ip = in + row * in_stride;
    T* op = out + row * out_stride;
    int t = threadIdx.x;
    __shared__ float red[8];
    float v[3];
#pragma unroll
    for (int i = 0; i < 3; i++) v[i] = ip[t + i * 256];
    float s = v[0] + v[1] + v[2];
    float s2 = v[0] * v[0] + v[1] * v[1] + v[2] * v[2];
    block_red2(s, s2, red);
    float mu = s * (1.f / Dd);
    float var = s2 * (1.f / Dd) - mu * mu;
    float r = rsqrtf(var + EPSf);
#pragma unroll
    for (int i = 0; i < 3; i++) {
        int d = t + i * 256;
        op[d] = (T)((v[i] - mu) * r * g[d] + bb[d]);
    }
}

// ---------------- embed assemble: LN(tmp)+pos, cls+pos ----------------
__global__ __launch_bounds__(256) void k_embed(
        const float* __restrict__ tmp, const float* __restrict__ cls,
        const float* __restrict__ pos, const float* __restrict__ g,
        const float* __restrict__ bb, float* __restrict__ x) {
    int pid = blockIdx.x;
    int b = pid / Nn, n = pid % Nn;
    int t = threadIdx.x;
    float* xp = x + (long)pid * Dd;
    if (n == 0) {
#pragma unroll
        for (int i = 0; i < 3; i++) {
            int d = t + i * 256;
            xp[d] = cls[d] + pos[d];
        }
        return;
    }
    const float* ip = tmp + (long)(b * NPc + n - 1) * Dd;
    __shared__ float red[8];
    float v[3];
#pragma unroll
    for (int i = 0; i < 3; i++) v[i] = ip[t + i * 256];
    float s = v[0] + v[1] + v[2];
    float s2 = v[0] * v[0] + v[1] * v[1] + v[2] * v[2];
    block_red2(s, s2, red);
    float mu = s * (1.f / Dd);
    float var = s2 * (1.f / Dd) - mu * mu;
    float r = rsqrtf(var + EPSf);
#pragma unroll
    for (int i = 0; i < 3; i++) {
        int d = t + i * 256;
        xp[d] = (v[i] - mu) * r * g[d] + bb[d] + pos[(long)n * Dd + d];
    }
}

// ---------------- weight prep: fp32 W[K][N] -> f16 Wt[N][K] ----------------
__global__ __launch_bounds__(256) void k_wprep(
        const float* __restrict__ W, half_t* __restrict__ Wt, int K, int N) {
    W += (long)blockIdx.z * K * N;
    Wt += (long)blockIdx.z * K * N;
    __shared__ float tile[32][33];
    int n = blockIdx.x * 32 + threadIdx.x;
    int k0 = blockIdx.y * 32;
#pragma unroll
    for (int i = 0; i < 4; i++)
        tile[threadIdx.y + i * 8][threadIdx.x] = W[(long)(k0 + threadIdx.y + i * 8) * N + n];
    __syncthreads();
    int kk = k0 + threadIdx.x;
#pragma unroll
    for (int i = 0; i < 4; i++)
        Wt[(long)(blockIdx.x * 32 + threadIdx.y + i * 8) * K + kk] =
            (half_t)tile[threadIdx.x][threadIdx.y + i * 8];
}

// ---------------- head weight prep: fp32 [768][1000] -> f16 [1024][768] (pad 0) --------
__global__ __launch_bounds__(256) void k_wprep_head(
        const float* __restrict__ W, half_t* __restrict__ Wt) {
    __shared__ float tile[32][33];
    int n = blockIdx.x * 32 + threadIdx.x;
    int k0 = blockIdx.y * 32;
#pragma unroll
    for (int i = 0; i < 4; i++)
        tile[threadIdx.y + i * 8][threadIdx.x] =
            (n < NCLS) ? W[(long)(k0 + threadIdx.y + i * 8) * NCLS + n] : 0.f;
    __syncthreads();
    int kk = k0 + threadIdx.x;
#pragma unroll
    for (int i = 0; i < 4; i++)
        Wt[(long)(blockIdx.x * 32 + threadIdx.y + i * 8) * Dd + kk] =
            (half_t)tile[threadIdx.x][threadIdx.y + i * 8];
}

// ---------------- head GEMM: one thread per (row,col), f16 dot ----------------
__global__ __launch_bounds__(256) void k_head(
        const half_t* __restrict__ Ah, const half_t* __restrict__ Wh,
        const float* __restrict__ bias, float* __restrict__ out) {
    int idx = blockIdx.x * 256 + threadIdx.x;
    int row = idx >> 10, col = idx & 1023;
    if (col >= NCLS) return;
    const half_t* ap = Ah + (long)row * Dd;
    const half_t* wp = Wh + (long)col * Dd;
    float acc = 0.f;
#pragma unroll
    for (int k = 0; k < 96; k++) {
        half8 a = *(const half8*)&ap[k * 8];
        half8 w = *(const half8*)&wp[k * 8];
#pragma unroll
        for (int u = 0; u < 8; u++) acc += (float)a[u] * (float)w[u];
    }
    out[(long)row * NCLS + col] = acc + bias[col];
}

// ---------------- LN+pack helper: 8 fp32 -> LN -> half8 ----------------
__device__ __forceinline__ uint32x4 ln_pack(const float* xp, float mu, float rs,
                                            f32x4 g0, f32x4 g1, f32x4 b0, f32x4 b1) {
    f32x4 v0 = *(const f32x4*)xp;
    f32x4 v1 = *(const f32x4*)(xp + 4);
    union { uint32x4 u; half8 h; } t;
#pragma unroll
    for (int u2 = 0; u2 < 4; u2++) {
        t.h[u2]     = (half_t)((v0[u2] - mu) * rs * g0[u2] + b0[u2]);
        t.h[u2 + 4] = (half_t)((v1[u2] - mu) * rs * g1[u2] + b1[u2]);
    }
    return t.u;
}

// ---------------- f16 MFMA GEMM ----------------
// LNF=1: A is fp32 x, LayerNorm (lng,lnb) fused into A-staging.
// OMODE=1 (qkv): C=q, C1=k head-major [b,h,n,64]; V third (n0>=1536) staged
//   TRANSPOSED in LDS then written lane-coalesced into Vt [b,h,64,224].
__device__ __forceinline__ half8 lds_frag(const uint32x4 (*L)[8], int row, int slot) {
    union { uint32x4 u; half8 h; } t;
    t.u = L[row][slot];
    return t.h;
}

template <int HASB, int HASR, typename CT, int OMODE, int LNF>
__global__ __launch_bounds__(256, 2) void k_hgemm(
        const void* __restrict__ Av, const half_t* __restrict__ Bt,
        const float* __restrict__ bias, const float* __restrict__ res,
        const float* __restrict__ lng, const float* __restrict__ lnb,
        CT* __restrict__ C, CT* __restrict__ C1, half_t* __restrict__ Vt,
        int M, int N, int K) {
    __shared__ uint32x4 smem[2176];
    __shared__ float murs[128][2];
    uint32x4 (*As)[8] = (uint32x4(*)[8])smem;
    uint32x4 (*Bs)[8] = (uint32x4(*)[8])(smem + 1024);
    const half_t* Ah = (const half_t*)Av;
    const float*  Af = (const float*)Av;
    const int tid = threadIdx.x;
    const int nwg = gridDim.x;
    const int q8 = nwg >> 3, r8 = nwg & 7;
    const int xc = blockIdx.x & 7, oo = blockIdx.x >> 3;
    const int tile = (xc < r8 ? xc * (q8 + 1) : r8 * (q8 + 1) + (xc - r8) * q8) + oo;
    const int gx = N >> 7;
    const int n0 = (tile % gx) * 128, m0 = (tile / gx) * 128;
    const int lane = tid & 63, w = tid >> 6;
    const int wrr = (w >> 1) * 64, wcc = (w & 1) * 64;
    const int lrow = lane & 15, lgrp = lane >> 4;

    // ---- LN prologue: mean/rsqrt-var for this block's 128 A-rows ----
    if constexpr (LNF) {
        int rowp = tid >> 1, hf = tid & 1;
        const float* xr = Af + (long)min(m0 + rowp, M - 1) * K + hf * (K / 2);
        float s = 0.f, s2 = 0.f;
        for (int k = 0; k < K / 2; k += 8) {
            f32x4 v0 = *(const f32x4*)(xr + k);
            f32x4 v1 = *(const f32x4*)(xr + k + 4);
#pragma unroll
            for (int u = 0; u < 4; u++) {
                s += v0[u] + v1[u];
                s2 += v0[u] * v0[u] + v1[u] * v1[u];
            }
        }
        s += __shfl_xor(s, 1);
        s2 += __shfl_xor(s2, 1);
        if (hf == 0) {
            float mu = s * (1.f / K);
            float var = s2 * (1.f / K) - mu * mu;
            murs[rowp][0] = mu;
            murs[rowp][1] = rsqrtf(var + EPSf);
        }
        __syncthreads();
    }

    int lm[4], sw[4];
    long gA[4], gB[4];
    const int cb = (tid & 7) * 8;
#pragma unroll
    for (int c = 0; c < 4; ++c) {
        lm[c] = c * 32 + (tid >> 3);
        sw[c] = (tid & 7) ^ (lm[c] & 7);
        int ma = m0 + lm[c];
        if (ma > M - 1) ma = M - 1;
        gA[c] = (long)ma * K + cb;
        gB[c] = (long)(n0 + lm[c]) * K + cb;
    }
    float muc[4], rsc[4];
    if constexpr (LNF) {
#pragma unroll
        for (int c = 0; c < 4; ++c) { muc[c] = murs[lm[c]][0]; rsc[c] = murs[lm[c]][1]; }
    }

    f32x4 acc[4][4] = {};
    uint32x4 ha[4], rb[4];
    f32x4 gv0, gv1, bv0, bv1;
    if constexpr (LNF) {
        gv0 = *(const f32x4*)(lng + cb);  gv1 = *(const f32x4*)(lng + cb + 4);
        bv0 = *(const f32x4*)(lnb + cb);  bv1 = *(const f32x4*)(lnb + cb + 4);
    }
#pragma unroll
    for (int c = 0; c < 4; ++c) {
        if constexpr (LNF)
            ha[c] = ln_pack(Af + gA[c], muc[c], rsc[c], gv0, gv1, bv0, bv1);
        else
            ha[c] = *(const uint32x4*)(Ah + gA[c]);
        rb[c] = *(const uint32x4*)(Bt + gB[c]);
    }
#pragma unroll
    for (int c = 0; c < 4; ++c) { As[lm[c]][sw[c]] = ha[c]; Bs[lm[c]][sw[c]] = rb[c]; }
    __syncthreads();

    const int nst = K >> 6;
    for (int t = 0; t < nst; ++t) {
        if (t + 1 < nst) {
            const int k0 = (t + 1) << 6;
            if constexpr (LNF) {
                gv0 = *(const f32x4*)(lng + k0 + cb);  gv1 = *(const f32x4*)(lng + k0 + cb + 4);
                bv0 = *(const f32x4*)(lnb + k0 + cb);  bv1 = *(const f32x4*)(lnb + k0 + cb + 4);
            }
#pragma unroll
            for (int c = 0; c < 4; ++c) {
                if constexpr (LNF)
                    ha[c] = ln_pack(Af + gA[c] + k0, muc[c], rsc[c], gv0, gv1, bv0, bv1);
                else
                    ha[c] = *(const uint32x4*)(Ah + gA[c] + k0);
                rb[c] = *(const uint32x4*)(Bt + gB[c] + k0);
            }
        }
#pragma unroll
        for (int kh = 0; kh < 2; ++kh) {
            half8 af[4], bf[4];
#pragma unroll
            for (int i2 = 0; i2 < 4; ++i2) {
                int m = wrr + i2 * 16 + lrow;
                af[i2] = lds_frag(As, m, (kh * 4 + lgrp) ^ (m & 7));
                int n = wcc + i2 * 16 + lrow;
                bf[i2] = lds_frag(Bs, n, (kh * 4 + lgrp) ^ (n & 7));
            }
#pragma unroll
            for (int i2 = 0; i2 < 4; ++i2)
#pragma unroll
                for (int j2 = 0; j2 < 4; ++j2)
                    acc[i2][j2] = __builtin_amdgcn_mfma_f32_16x16x32_f16(af[i2], bf[j2], acc[i2][j2], 0, 0, 0);
        }
        if (t + 1 < nst) {
            __syncthreads();
#pragma unroll
            for (int c = 0; c < 4; ++c) { As[lm[c]][sw[c]] = ha[c]; Bs[lm[c]][sw[c]] = rb[c]; }
            __syncthreads();
        }
    }

    if constexpr (sizeof(CT) == 2) {
        if constexpr (OMODE == 1) {
            if (n0 >= 1536) {
                // V third: stage TRANSPOSED in LDS (Cs[col][token], stride 136),
                // then lane-coalesced scalar stores (consecutive lanes = consecutive nn).
                __syncthreads();
                half_t* Cs = (half_t*)smem;
#pragma unroll
                for (int i2 = 0; i2 < 4; ++i2)
#pragma unroll
                    for (int j2 = 0; j2 < 4; ++j2) {
                        int colc = wcc + j2 * 16 + lrow;
#pragma unroll
                        for (int q = 0; q < 4; ++q) {
                            int r = wrr + i2 * 16 + lgrp * 4 + q;
                            Cs[colc * 136 + r] = (half_t)acc[i2][j2][q];
                        }
                    }
                __syncthreads();
                const int rr = tid & 127;      // token offset (lane-consecutive)
                const int cbase = (tid >> 7) * 64;
                int token = m0 + rr;
                bool ok = token < M;
                int b = 0, nn = 0;
                if (ok) { b = token / Nn; nn = token - b * Nn; }
#pragma unroll
                for (int cc = 0; cc < 64; ++cc) {
                    int c = cbase + cc;
                    int rem = n0 + c - 1536;
                    int h = rem >> 6, d = rem & 63;
                    if (ok)
                        Vt[((long)(b * NH + h) * 64 + d) * 224 + nn] = Cs[c * 136 + rr];
                }
                return;
            }
        }
        __syncthreads();
        half_t* Cs = (half_t*)smem;
#pragma unroll
        for (int i2 = 0; i2 < 4; ++i2)
#pragma unroll
            for (int j2 = 0; j2 < 4; ++j2) {
                int colc = wcc + j2 * 16 + lrow;
                float bv = HASB ? bias[n0 + colc] : 0.f;
#pragma unroll
                for (int q = 0; q < 4; ++q) {
                    int r = wrr + i2 * 16 + lgrp * 4 + q;
                    Cs[r * 136 + colc] = (half_t)(acc[i2][j2][q] + bv);
                }
            }
        __syncthreads();
#pragma unroll
        for (int it = 0; it < 8; ++it) {
            int idx = tid + it * 256;
            int row = idx >> 4, cu = idx & 15;
            int token = m0 + row;
            if (token < M) {
                uint32x4 val = *(const uint32x4*)(Cs + row * 136 + cu * 8);
                if constexpr (OMODE == 1) {
                    int gc = n0 + cu * 8;
                    int which = gc >= 768 ? 1 : 0;
                    int rem = gc - which * 768;
                    int h = rem >> 6, d = rem & 63;
                    int b = token / Nn, nn = token - b * Nn;
                    CT* dst = (which == 0 ? C : C1);
                    __builtin_nontemporal_store(val,
                        (uint32x4*)(dst + (((long)(b * NH + h) * Nn + nn) << 6) + d));
                } else {
                    __builtin_nontemporal_store(val,
                        (uint32x4*)(C + (long)token * N + n0 + cu * 8));
                }
            }
        }
    } else {
#pragma unroll
        for (int i2 = 0; i2 < 4; ++i2)
#pragma unroll
            for (int j2 = 0; j2 < 4; ++j2) {
                int colc = n0 + wcc + j2 * 16 + lrow;
                float bv = HASB ? bias[colc] : 0.f;
#pragma unroll
                for (int q = 0; q < 4; ++q) {
                    int r = m0 + wrr + i2 * 16 + lgrp * 4 + q;
                    if (r < M) {
                        float v = acc[i2][j2][q] + bv;
                        if (HASR) v += res[(long)r * N + colc];
                        __builtin_nontemporal_store(v, &C[(long)r * N + colc]);
                    }
                }
            }
    }
}

// ---------------- attention stats: cross-head mu & rsqrt(var), fragment layout --------
__global__ __launch_bounds__(256) void k_stats(
        const half_t* __restrict__ qh, const half_t* __restrict__ kh,
        f32x4* __restrict__ muT, f32x4* __restrict__ rsT) {
    const int blk = (blockIdx.x & 7) * 169 + (blockIdx.x >> 3);   // 1352 = 8*169
    const int w = threadIdx.x >> 6, lane = threadIdx.x & 63;
    const int task = blk * 4 + w;                                  // 5408 = 32*169
    const int b = task / 169, r = task % 169;
    const int it = r / 13, jt = r % 13;
    const int lrow = lane & 15, lg = lane >> 4;
    const int i0 = it * 16, j0 = jt * 16;
    const int arow = min(i0 + lrow, Nn - 1);
    const int jr = min(j0 + lrow, Nn - 1);
    const int hbase = b * NH;

    float sv[4] = {}, sq[4] = {};
#pragma unroll
    for (int h = 0; h < NH; h++) {
        const half_t* Qp = qh + ((long)(hbase + h) * Nn) * 64;
        const half_t* Kp = kh + ((long)(hbase + h) * Nn) * 64;
        half8 af0 = *(const half8*)&Qp[(long)arow * 64 + lg * 8];
        half8 af1 = *(const half8*)&Qp[(long)arow * 64 + 32 + lg * 8];
        half8 bf0 = *(const half8*)&Kp[(long)jr * 64 + lg * 8];
        half8 bf1 = *(const half8*)&Kp[(long)jr * 64 + 32 + lg * 8];
        f32x4 acc = {};
        acc = __builtin_amdgcn_mfma_f32_16x16x32_f16(af0, bf0, acc, 0, 0, 0);
        acc = __builtin_amdgcn_mfma_f32_16x16x32_f16(af1, bf1, acc, 0, 0, 0);
#pragma unroll
        for (int q = 0; q < 4; q++) { sv[q] += acc[q]; sq[q] += acc[q] * acc[q]; }
    }
    f32x4 muv, rsv;
#pragma unroll
    for (int q = 0; q < 4; q++) {
        float mu = sv[q] * (1.f / NH);
        float var = (sq[q] - sv[q] * mu) * (1.f / (NH - 1));
        muv[q] = mu;
        rsv[q] = rsqrtf(var);
    }
    long idx = ((long)(b * 13 + it) * 13 + jt) * 64 + lane;
    muT[idx] = muv;
    rsT[idx] = rsv;
}

// ---------------- attention per head: S recompute + z-score + softmax + PV ----------------
__global__ __launch_bounds__(64) void k_attn2(
        const half_t* __restrict__ qh, const half_t* __restrict__ kh,
        const half_t* __restrict__ vt, const f32x4* __restrict__ muT,
        const f32x4* __restrict__ rsT, half_t* __restrict__ o) {
    __shared__ half_t PB[16][232];
    const int tile = (blockIdx.x & 7) * 624 + (blockIdx.x >> 3);  // 4992 = 8*624
    const int bh = tile / 13, it = tile % 13;
    const int b = bh / NH, h = bh % NH;
    const int i0 = it * 16;
    const int lane = threadIdx.x;
    const int lrow = lane & 15, lg = lane >> 4;
    const int arow = min(i0 + lrow, Nn - 1);

    for (int idx = lane; idx < 16 * 12; idx += 64) {
        int rr = idx / 12, u = idx % 12;
        *(unsigned int*)&PB[rr][208 + u * 2] = 0u;
    }

    const half_t* Qp = qh + ((long)bh * Nn) * 64;
    const half_t* Kp = kh + ((long)bh * Nn) * 64;
    half8 af0 = *(const half8*)&Qp[(long)arow * 64 + lg * 8];
    half8 af1 = *(const half8*)&Qp[(long)arow * 64 + 32 + lg * 8];
    const f32x4* muB = muT + ((long)(b * 13 + it) * 13) * 64 + lane;
    const f32x4* rsB = rsT + ((long)(b * 13 + it) * 13) * 64 + lane;

    float ez[13][4];
    float mx[4] = {-1e30f, -1e30f, -1e30f, -1e30f};
#pragma unroll
    for (int jt = 0; jt < 13; jt++) {
        int jr = min(jt * 16 + lrow, Nn - 1);
        half8 bf0 = *(const half8*)&Kp[(long)jr * 64 + lg * 8];
        half8 bf1 = *(const half8*)&Kp[(long)jr * 64 + 32 + lg * 8];
        f32x4 acc = {};
        acc = __builtin_amdgcn_mfma_f32_16x16x32_f16(af0, bf0, acc, 0, 0, 0);
        acc = __builtin_amdgcn_mfma_f32_16x16x32_f16(af1, bf1, acc, 0, 0, 0);
        f32x4 mu4 = muB[jt * 64];
        f32x4 rs4 = rsB[jt * 64];
        bool joob = (jt * 16 + lrow) > Nn - 1;
#pragma unroll
        for (int q = 0; q < 4; q++) {
            float z = (acc[q] - mu4[q]) * rs4[q];
            if (joob) z = -1e30f;
            ez[jt][q] = z;
            mx[q] = fmaxf(mx[q], z);
        }
    }
#pragma unroll
    for (int st = 1; st <= 8; st <<= 1)
#pragma unroll
        for (int q = 0; q < 4; q++) mx[q] = fmaxf(mx[q], __shfl_xor(mx[q], st));
    float sm[4] = {0.f, 0.f, 0.f, 0.f};
#pragma unroll
    for (int jt = 0; jt < 13; jt++)
#pragma unroll
        for (int q = 0; q < 4; q++) {
            float e = __expf(ez[jt][q] - mx[q]);
            ez[jt][q] = e;
            sm[q] += e;
        }
#pragma unroll
    for (int st = 1; st <= 8; st <<= 1)
#pragma unroll
        for (int q = 0; q < 4; q++) sm[q] += __shfl_xor(sm[q], st);
    float inv[4];
#pragma unroll
    for (int q = 0; q < 4; q++) inv[q] = 1.f / sm[q];
#pragma unroll
    for (int jt = 0; jt < 13; jt++)
#pragma unroll
        for (int q = 0; q < 4; q++)
            PB[lg * 4 + q][jt * 16 + lrow] = (half_t)(ez[jt][q] * inv[q]);
    __syncthreads();

    const half_t* Vtp = vt + ((long)bh * 64) * 224;
#pragma unroll
    for (int dt = 0; dt < 4; dt++) {
        f32x4 oacc = {};
#pragma unroll
        for (int kt = 0; kt < 7; kt++) {
            half8 pa = *(const half8*)&PB[lrow][kt * 32 + lg * 8];
            half8 vb = *(const half8*)&Vtp[(long)(dt * 16 + lrow) * 224 + kt * 32 + lg * 8];
            oacc = __builtin_amdgcn_mfma_f32_16x16x32_f16(pa, vb, oacc, 0, 0, 0);
        }
#pragma unroll
        for (int q = 0; q < 4; q++) {
            int i = i0 + lg * 4 + q;
            if (i < Nn)
                o[((long)(b * Nn) + i) * INNERc + h * 64 + dt * 16 + lrow] = (half_t)oacc[q];
        }
    }
}

// ---------------- host launcher ----------------
extern "C" void kernel_launch(void* const* d_in, const int* in_sizes, int n_in,
                              void* d_out, int out_size, void* d_ws, size_t ws_size,
                              hipStream_t stream) {
    const float* img     = (const float*)d_in[0];
    const float* patch_g = (const float*)d_in[2];
    const float* patch_b = (const float*)d_in[3];
    const float* W_patch = (const float*)d_in[4];
    const float* b_patch = (const float*)d_in[5];
    const float* emb_g   = (const float*)d_in[6];
    const float* emb_b   = (const float*)d_in[7];
    const float* pos     = (const float*)d_in[8];
    const float* cls     = (const float*)d_in[9];
    const float* ln_g    = (const float*)d_in[10];
    const float* ln_b    = (const float*)d_in[11];
    const float* W_qkv   = (const float*)d_in[12];
    const float* W_out   = (const float*)d_in[13];
    const float* b_out   = (const float*)d_in[14];
    const float* fin_g   = (const float*)d_in[15];
    const float* fin_b   = (const float*)d_in[16];
    const float* W_head  = (const float*)d_in[17];
    const float* b_head  = (const float*)d_in[18];
    float* out = (float*)d_out;

    const long SZ_XD  = (long)Bc * Nn * Dd;            // 4,841,472
    const long SZ_HD  = (long)Bc * NH * Nn * DHd;      // 4,841,472
    const long SZ_VT  = (long)Bc * NH * 64 * 224;      // 5,505,024
    const long SZ_TMP = (long)Bc * NPc * Dd;
    const long SZ_MU  = (long)Bc * 169 * 256 + 1024;   // fragment-layout stats

    float* x    = (float*)d_ws;
    float* tmp  = x + SZ_XD;
    float* muG  = tmp + SZ_TMP;
    float* rsG  = muG + SZ_MU;
    half_t* xh       = (half_t*)(rsG + SZ_MU);
    half_t* qhb      = xh + SZ_XD;
    half_t* khb      = qhb + SZ_HD;
    half_t* vtb      = khb + SZ_HD;
    half_t* clsh     = vtb + SZ_VT;                         // 32x768 f16
    half_t* wh_head  = clsh + 32 * Dd;                      // 1024x768 f16
    half_t* wt_patch = wh_head + 1024 * Dd;
    half_t* wt_qkv   = wt_patch + (long)Dd * Dd;
    half_t* wt_out   = wt_qkv + (long)DEPTHc * 3 * INNERc * Dd;

    // ---- weight prep ----
    hipLaunchKernelGGL(k_wprep, dim3(Dd / 32, Dd / 32, 1), dim3(32, 8), 0, stream,
                       W_patch, wt_patch, Dd, Dd);
    hipLaunchKernelGGL(k_wprep, dim3(3 * INNERc / 32, Dd / 32, DEPTHc), dim3(32, 8), 0, stream,
                       W_qkv, wt_qkv, Dd, 3 * INNERc);
    hipLaunchKernelGGL(k_wprep, dim3(Dd / 32, Dd / 32, DEPTHc), dim3(32, 8), 0, stream,
                       W_out, wt_out, Dd, Dd);
    hipLaunchKernelGGL(k_wprep_head, dim3(32, 24), dim3(32, 8), 0, stream,
                       W_head, wh_head);

    // 1. patchify + patch LN -> xh (f16)
    hipLaunchKernelGGL(k_patch_ln, dim3(Bc * NPc), dim3(256), 0, stream,
                       img, patch_g, patch_b, xh);
    // 2. patch GEMM (+b_patch) -> tmp fp32
    hipLaunchKernelGGL((k_hgemm<1, 0, float, 0, 0>), dim3(6 * 49), dim3(256), 0, stream,
                       xh, wt_patch, b_patch, nullptr, nullptr, nullptr,
                       tmp, nullptr, nullptr, Bc * NPc, Dd, Dd);
    // 3. emb LN + cls concat + pos add -> x
    hipLaunchKernelGGL(k_embed, dim3(Bc * Nn), dim3(256), 0, stream,
                       tmp, cls, pos, emb_g, emb_b, x);

    const int Mrows = Bc * Nn;  // 6304
    for (int l = 0; l < DEPTHc; l++) {
        const float* g  = ln_g + (long)l * Dd;
        const float* bb = ln_b + (long)l * Dd;
        const half_t* Wq = wt_qkv + (long)l * 3 * INNERc * Dd;
        const half_t* Wo = wt_out + (long)l * Dd * Dd;
        const float* bo = b_out + (long)l * Dd;
        // fused LN + qkv GEMM; V staged in LDS, written transposed coalesced
        hipLaunchKernelGGL((k_hgemm<0, 0, half_t, 1, 1>), dim3(18 * 50), dim3(256), 0, stream,
                           x, Wq, nullptr, nullptr, g, bb,
                           qhb, khb, vtb, Mrows, 3 * INNERc, Dd);
        hipLaunchKernelGGL(k_stats, dim3(1352), dim3(256), 0, stream,
                           qhb, khb, (f32x4*)muG, (f32x4*)rsG);
        hipLaunchKernelGGL(k_attn2, dim3(4992), dim3(64), 0, stream,
                           qhb, khb, vtb, (const f32x4*)muG, (const f32x4*)rsG, xh);
        hipLaunchKernelGGL((k_hgemm<1, 1, float, 0, 0>), dim3(6 * 50), dim3(256), 0, stream,
                           xh, Wo, bo, x, nullptr, nullptr,
                           x, nullptr, nullptr, Mrows, Dd, Dd);
    }
    // final LN (cls rows only) -> clsh f16
    hipLaunchKernelGGL((k_ln<half_t>), dim3(Bc), dim3(256), 0, stream,
                       x, fin_g, fin_b, clsh, (long)Nn * Dd, (long)Dd);
    // head GEMM: f16 dot per (row,col)
    hipLaunchKernelGGL(k_head, dim3(128), dim3(256), 0, stream,
                       clsh, wh_head, b_head, out);
}

// Round 11
// 1774.840 us; speedup vs baseline: 1.8284x; 1.4396x over previous
//
#include <hip/hip_runtime.h>
#include <math.h>

// ---------------- problem constants ----------------
constexpr int Bc = 32, Cch = 3, Hh = 224, Ww = 224, Pp = 16;
constexpr int Dd = 768, NH = 12, DHd = 64, INNERc = 768;
constexpr int DEPTHc = 12, NCLS = 1000;
constexpr int NPc = 196, Nn = 197, PD = 768;
constexpr float EPSf = 1e-5f;

typedef _Float16 half_t;
typedef __attribute__((ext_vector_type(8))) _Float16 half8;
typedef __attribute__((ext_vector_type(4))) float f32x4;
typedef __attribute__((ext_vector_type(4))) unsigned int uint32x4;

// ---------------- reduction helpers ----------------
__device__ __forceinline__ float wave_red_sum(float v) {
#pragma unroll
    for (int m = 32; m; m >>= 1) v += __shfl_xor(v, m);
    return v;
}

__device__ __forceinline__ void block_red2(float& s, float& s2, float* red) {
    s = wave_red_sum(s);
    s2 = wave_red_sum(s2);
    int wid = threadIdx.x >> 6, lane = threadIdx.x & 63;
    if (lane == 0) { red[wid] = s; red[4 + wid] = s2; }
    __syncthreads();
    s = red[0] + red[1] + red[2] + red[3];
    s2 = red[4] + red[5] + red[6] + red[7];
}

// ---------------- patchify + patch LN -> f16 ----------------
__global__ __launch_bounds__(256) void k_patch_ln(
        const float* __restrict__ img, const float* __restrict__ g,
        const float* __restrict__ bb, half_t* __restrict__ out) {
    int pid = blockIdx.x;
    int b = pid / NPc, n = pid % NPc;
    int ph = n / 14, pw = n % 14;
    int t = threadIdx.x;
    __shared__ float red[8];
    float v[3];
#pragma unroll
    for (int i = 0; i < 3; i++) {
        int d = t + i * 256;
        int c = d % 3, q = (d / 3) & 15, p = d / 48;
        v[i] = img[((long)(b * Cch + c) * Hh + ph * Pp + p) * Ww + pw * Pp + q];
    }
    float s = v[0] + v[1] + v[2];
    float s2 = v[0] * v[0] + v[1] * v[1] + v[2] * v[2];
    block_red2(s, s2, red);
    float mu = s * (1.f / PD);
    float var = s2 * (1.f / PD) - mu * mu;
    float r = rsqrtf(var + EPSf);
#pragma unroll
    for (int i = 0; i < 3; i++) {
        int d = t + i * 256;
        out[(long)pid * PD + d] = (half_t)((v[i] - mu) * r * g[d] + bb[d]);
    }
}

// ---------------- row LayerNorm (768 wide), templated output ----------------
template <typename T>
__global__ __launch_bounds__(256) void k_ln(
        const float* __restrict__ in, const float* __restrict__ g,
        const float* __restrict__ bb, T* __restrict__ out,
        long in_stride, long out_stride) {
    long row = blockIdx.x;
    const float* ip = in + row * in_stride;
    T* op = out + row * out_stride;
    int t = threadIdx.x;
    __shared__ float red[8];
    float v[3];
#pragma unroll
    for (int i = 0; i < 3; i++) v[i] = ip[t + i * 256];
    float s = v[0] + v[1] + v[2];
    float s2 = v[0] * v[0] + v[1] * v[1] + v[2] * v[2];
    block_red2(s, s2, red);
    float mu = s * (1.f / Dd);
    float var = s2 * (1.f / Dd) - mu * mu;
    float r = rsqrtf(var + EPSf);
#pragma unroll
    for (int i = 0; i < 3; i++) {
        int d = t + i * 256;
        op[d] = (T)((v[i] - mu) * r * g[d] + bb[d]);
    }
}

// ---------------- embed assemble: LN(tmp)+pos, cls+pos ----------------
__global__ __launch_bounds__(256) void k_embed(
        const float* __restrict__ tmp, const float* __restrict__ cls,
        const float* __restrict__ pos, const float* __restrict__ g,
        const float* __restrict__ bb, float* __restrict__ x) {
    int pid = blockIdx.x;
    int b = pid / Nn, n = pid % Nn;
    int t = threadIdx.x;
    float* xp = x + (long)pid * Dd;
    if (n == 0) {
#pragma unroll
        for (int i = 0; i < 3; i++) {
            int d = t + i * 256;
            xp[d] = cls[d] + pos[d];
        }
        return;
    }
    const float* ip = tmp + (long)(b * NPc + n - 1) * Dd;
    __shared__ float red[8];
    float v[3];
#pragma unroll
    for (int i = 0; i < 3; i++) v[i] = ip[t + i * 256];
    float s = v[0] + v[1] + v[2];
    float s2 = v[0] * v[0] + v[1] * v[1] + v[2] * v[2];
    block_red2(s, s2, red);
    float mu = s * (1.f / Dd);
    float var = s2 * (1.f / Dd) - mu * mu;
    float r = rsqrtf(var + EPSf);
#pragma unroll
    for (int i = 0; i < 3; i++) {
        int d = t + i * 256;
        xp[d] = (v[i] - mu) * r * g[d] + bb[d] + pos[(long)n * Dd + d];
    }
}

// ---------------- weight prep: fp32 W[K][N] -> f16 Wt[N][K] ----------------
__global__ __launch_bounds__(256) void k_wprep(
        const float* __restrict__ W, half_t* __restrict__ Wt, int K, int N) {
    W += (long)blockIdx.z * K * N;
    Wt += (long)blockIdx.z * K * N;
    __shared__ float tile[32][33];
    int n = blockIdx.x * 32 + threadIdx.x;
    int k0 = blockIdx.y * 32;
#pragma unroll
    for (int i = 0; i < 4; i++)
        tile[threadIdx.y + i * 8][threadIdx.x] = W[(long)(k0 + threadIdx.y + i * 8) * N + n];
    __syncthreads();
    int kk = k0 + threadIdx.x;
#pragma unroll
    for (int i = 0; i < 4; i++)
        Wt[(long)(blockIdx.x * 32 + threadIdx.y + i * 8) * K + kk] =
            (half_t)tile[threadIdx.x][threadIdx.y + i * 8];
}

// ---------------- head weight prep: fp32 [768][1000] -> f16 [1024][768] (pad 0) --------
__global__ __launch_bounds__(256) void k_wprep_head(
        const float* __restrict__ W, half_t* __restrict__ Wt) {
    __shared__ float tile[32][33];
    int n = blockIdx.x * 32 + threadIdx.x;
    int k0 = blockIdx.y * 32;
#pragma unroll
    for (int i = 0; i < 4; i++)
        tile[threadIdx.y + i * 8][threadIdx.x] =
            (n < NCLS) ? W[(long)(k0 + threadIdx.y + i * 8) * NCLS + n] : 0.f;
    __syncthreads();
    int kk = k0 + threadIdx.x;
#pragma unroll
    for (int i = 0; i < 4; i++)
        Wt[(long)(blockIdx.x * 32 + threadIdx.y + i * 8) * Dd + kk] =
            (half_t)tile[threadIdx.x][threadIdx.y + i * 8];
}

// ---------------- head GEMM: one thread per (row,col), f16 dot ----------------
__global__ __launch_bounds__(256) void k_head(
        const half_t* __restrict__ Ah, const half_t* __restrict__ Wh,
        const float* __restrict__ bias, float* __restrict__ out) {
    int idx = blockIdx.x * 256 + threadIdx.x;
    int row = idx >> 10, col = idx & 1023;
    if (col >= NCLS) return;
    const half_t* ap = Ah + (long)row * Dd;
    const half_t* wp = Wh + (long)col * Dd;
    float acc = 0.f;
#pragma unroll
    for (int k = 0; k < 96; k++) {
        half8 a = *(const half8*)&ap[k * 8];
        half8 w = *(const half8*)&wp[k * 8];
#pragma unroll
        for (int u = 0; u < 8; u++) acc += (float)a[u] * (float)w[u];
    }
    out[(long)row * NCLS + col] = acc + bias[col];
}

// ---------------- f16 MFMA GEMM ----------------
// OMODE=1 (qkv): C=q, C1=k head-major [b,h,n,64]; V third (n0>=1536) staged
//   TRANSPOSED in LDS then written lane-coalesced into Vt [b,h,64,224].
__device__ __forceinline__ half8 lds_frag(const uint32x4 (*L)[8], int row, int slot) {
    union { uint32x4 u; half8 h; } t;
    t.u = L[row][slot];
    return t.h;
}

template <int HASB, int HASR, typename CT, int OMODE>
__global__ __launch_bounds__(256, 2) void k_hgemm(
        const half_t* __restrict__ A, const half_t* __restrict__ Bt,
        const float* __restrict__ bias, const float* __restrict__ res,
        CT* __restrict__ C, CT* __restrict__ C1, half_t* __restrict__ Vt,
        int M, int N, int K) {
    __shared__ uint32x4 smem[2176];
    uint32x4 (*As)[8] = (uint32x4(*)[8])smem;
    uint32x4 (*Bs)[8] = (uint32x4(*)[8])(smem + 1024);
    const int tid = threadIdx.x;
    const int nwg = gridDim.x;
    const int q8 = nwg >> 3, r8 = nwg & 7;
    const int xc = blockIdx.x & 7, oo = blockIdx.x >> 3;
    const int tile = (xc < r8 ? xc * (q8 + 1) : r8 * (q8 + 1) + (xc - r8) * q8) + oo;
    const int gx = N >> 7;
    const int n0 = (tile % gx) * 128, m0 = (tile / gx) * 128;
    const int lane = tid & 63, w = tid >> 6;
    const int wrr = (w >> 1) * 64, wcc = (w & 1) * 64;
    const int lrow = lane & 15, lgrp = lane >> 4;

    int lm[4], sw[4];
    long gA[4], gB[4];
    const int cb = (tid & 7) * 8;
#pragma unroll
    for (int c = 0; c < 4; ++c) {
        lm[c] = c * 32 + (tid >> 3);
        sw[c] = (tid & 7) ^ (lm[c] & 7);
        int ma = m0 + lm[c];
        if (ma > M - 1) ma = M - 1;
        gA[c] = (long)ma * K + cb;
        gB[c] = (long)(n0 + lm[c]) * K + cb;
    }

    f32x4 acc[4][4] = {};
    uint32x4 ra[4], rb[4];
#pragma unroll
    for (int c = 0; c < 4; ++c) { ra[c] = *(const uint32x4*)(A + gA[c]); rb[c] = *(const uint32x4*)(Bt + gB[c]); }
#pragma unroll
    for (int c = 0; c < 4; ++c) { As[lm[c]][sw[c]] = ra[c]; Bs[lm[c]][sw[c]] = rb[c]; }
    __syncthreads();

    const int nst = K >> 6;
    for (int t = 0; t < nst; ++t) {
        if (t + 1 < nst) {
            const int k0 = (t + 1) << 6;
#pragma unroll
            for (int c = 0; c < 4; ++c) {
                ra[c] = *(const uint32x4*)(A + gA[c] + k0);
                rb[c] = *(const uint32x4*)(Bt + gB[c] + k0);
            }
        }
#pragma unroll
        for (int kh = 0; kh < 2; ++kh) {
            half8 af[4], bf[4];
#pragma unroll
            for (int i2 = 0; i2 < 4; ++i2) {
                int m = wrr + i2 * 16 + lrow;
                af[i2] = lds_frag(As, m, (kh * 4 + lgrp) ^ (m & 7));
                int n = wcc + i2 * 16 + lrow;
                bf[i2] = lds_frag(Bs, n, (kh * 4 + lgrp) ^ (n & 7));
            }
#pragma unroll
            for (int i2 = 0; i2 < 4; ++i2)
#pragma unroll
                for (int j2 = 0; j2 < 4; ++j2)
                    acc[i2][j2] = __builtin_amdgcn_mfma_f32_16x16x32_f16(af[i2], bf[j2], acc[i2][j2], 0, 0, 0);
        }
        if (t + 1 < nst) {
            __syncthreads();
#pragma unroll
            for (int c = 0; c < 4; ++c) { As[lm[c]][sw[c]] = ra[c]; Bs[lm[c]][sw[c]] = rb[c]; }
            __syncthreads();
        }
    }

    if constexpr (sizeof(CT) == 2) {
        if constexpr (OMODE == 1) {
            if (n0 >= 1536) {
                // V third: stage TRANSPOSED in LDS (Cs[col][token], stride 136),
                // then lane-coalesced scalar stores (consecutive lanes = consecutive nn).
                __syncthreads();
                half_t* Cs = (half_t*)smem;
#pragma unroll
                for (int i2 = 0; i2 < 4; ++i2)
#pragma unroll
                    for (int j2 = 0; j2 < 4; ++j2) {
                        int colc = wcc + j2 * 16 + lrow;
#pragma unroll
                        for (int q = 0; q < 4; ++q) {
                            int r = wrr + i2 * 16 + lgrp * 4 + q;
                            Cs[colc * 136 + r] = (half_t)acc[i2][j2][q];
                        }
                    }
                __syncthreads();
                const int rr = tid & 127;      // token offset (lane-consecutive)
                const int cbase = (tid >> 7) * 64;
                int token = m0 + rr;
                bool ok = token < M;
                int b = 0, nn = 0;
                if (ok) { b = token / Nn; nn = token - b * Nn; }
#pragma unroll
                for (int cc = 0; cc < 64; ++cc) {
                    int c = cbase + cc;
                    int rem = n0 + c - 1536;
                    int h = rem >> 6, d = rem & 63;
                    if (ok)
                        Vt[((long)(b * NH + h) * 64 + d) * 224 + nn] = Cs[c * 136 + rr];
                }
                return;
            }
        }
        __syncthreads();
        half_t* Cs = (half_t*)smem;
#pragma unroll
        for (int i2 = 0; i2 < 4; ++i2)
#pragma unroll
            for (int j2 = 0; j2 < 4; ++j2) {
                int colc = wcc + j2 * 16 + lrow;
                float bv = HASB ? bias[n0 + colc] : 0.f;
#pragma unroll
                for (int q = 0; q < 4; ++q) {
                    int r = wrr + i2 * 16 + lgrp * 4 + q;
                    Cs[r * 136 + colc] = (half_t)(acc[i2][j2][q] + bv);
                }
            }
        __syncthreads();
#pragma unroll
        for (int it = 0; it < 8; ++it) {
            int idx = tid + it * 256;
            int row = idx >> 4, cu = idx & 15;
            int token = m0 + row;
            if (token < M) {
                uint32x4 val = *(const uint32x4*)(Cs + row * 136 + cu * 8);
                if constexpr (OMODE == 1) {
                    int gc = n0 + cu * 8;
                    int which = gc >= 768 ? 1 : 0;
                    int rem = gc - which * 768;
                    int h = rem >> 6, d = rem & 63;
                    int b = token / Nn, nn = token - b * Nn;
                    CT* dst = (which == 0 ? C : C1);
                    __builtin_nontemporal_store(val,
                        (uint32x4*)(dst + (((long)(b * NH + h) * Nn + nn) << 6) + d));
                } else {
                    __builtin_nontemporal_store(val,
                        (uint32x4*)(C + (long)token * N + n0 + cu * 8));
                }
            }
        }
    } else {
#pragma unroll
        for (int i2 = 0; i2 < 4; ++i2)
#pragma unroll
            for (int j2 = 0; j2 < 4; ++j2) {
                int colc = n0 + wcc + j2 * 16 + lrow;
                float bv = HASB ? bias[colc] : 0.f;
#pragma unroll
                for (int q = 0; q < 4; ++q) {
                    int r = m0 + wrr + i2 * 16 + lgrp * 4 + q;
                    if (r < M) {
                        float v = acc[i2][j2][q] + bv;
                        if (HASR) v += res[(long)r * N + colc];
                        __builtin_nontemporal_store(v, &C[(long)r * N + colc]);
                    }
                }
            }
    }
}

// ---------------- attention stats: cross-head mu & rsqrt(var), fragment layout --------
__global__ __launch_bounds__(256) void k_stats(
        const half_t* __restrict__ qh, const half_t* __restrict__ kh,
        f32x4* __restrict__ muT, f32x4* __restrict__ rsT) {
    const int blk = (blockIdx.x & 7) * 169 + (blockIdx.x >> 3);   // 1352 = 8*169
    const int w = threadIdx.x >> 6, lane = threadIdx.x & 63;
    const int task = blk * 4 + w;                                  // 5408 = 32*169
    const int b = task / 169, r = task % 169;
    const int it = r / 13, jt = r % 13;
    const int lrow = lane & 15, lg = lane >> 4;
    const int i0 = it * 16, j0 = jt * 16;
    const int arow = min(i0 + lrow, Nn - 1);
    const int jr = min(j0 + lrow, Nn - 1);
    const int hbase = b * NH;

    float sv[4] = {}, sq[4] = {};
#pragma unroll
    for (int h = 0; h < NH; h++) {
        const half_t* Qp = qh + ((long)(hbase + h) * Nn) * 64;
        const half_t* Kp = kh + ((long)(hbase + h) * Nn) * 64;
        half8 af0 = *(const half8*)&Qp[(long)arow * 64 + lg * 8];
        half8 af1 = *(const half8*)&Qp[(long)arow * 64 + 32 + lg * 8];
        half8 bf0 = *(const half8*)&Kp[(long)jr * 64 + lg * 8];
        half8 bf1 = *(const half8*)&Kp[(long)jr * 64 + 32 + lg * 8];
        f32x4 acc = {};
        acc = __builtin_amdgcn_mfma_f32_16x16x32_f16(af0, bf0, acc, 0, 0, 0);
        acc = __builtin_amdgcn_mfma_f32_16x16x32_f16(af1, bf1, acc, 0, 0, 0);
#pragma unroll
        for (int q = 0; q < 4; q++) { sv[q] += acc[q]; sq[q] += acc[q] * acc[q]; }
    }
    f32x4 muv, rsv;
#pragma unroll
    for (int q = 0; q < 4; q++) {
        float mu = sv[q] * (1.f / NH);
        float var = (sq[q] - sv[q] * mu) * (1.f / (NH - 1));
        muv[q] = mu;
        rsv[q] = rsqrtf(var);
    }
    long idx = ((long)(b * 13 + it) * 13 + jt) * 64 + lane;
    muT[idx] = muv;
    rsT[idx] = rsv;
}

// ---------------- attention per head: S recompute + z-score + softmax + PV ----------------
__global__ __launch_bounds__(64) void k_attn2(
        const half_t* __restrict__ qh, const half_t* __restrict__ kh,
        const half_t* __restrict__ vt, const f32x4* __restrict__ muT,
        const f32x4* __restrict__ rsT, half_t* __restrict__ o) {
    __shared__ half_t PB[16][232];
    const int tile = (blockIdx.x & 7) * 624 + (blockIdx.x >> 3);  // 4992 = 8*624
    const int bh = tile / 13, it = tile % 13;
    const int b = bh / NH, h = bh % NH;
    const int i0 = it * 16;
    const int lane = threadIdx.x;
    const int lrow = lane & 15, lg = lane >> 4;
    const int arow = min(i0 + lrow, Nn - 1);

    for (int idx = lane; idx < 16 * 12; idx += 64) {
        int rr = idx / 12, u = idx % 12;
        *(unsigned int*)&PB[rr][208 + u * 2] = 0u;
    }

    const half_t* Qp = qh + ((long)bh * Nn) * 64;
    const half_t* Kp = kh + ((long)bh * Nn) * 64;
    half8 af0 = *(const half8*)&Qp[(long)arow * 64 + lg * 8];
    half8 af1 = *(const half8*)&Qp[(long)arow * 64 + 32 + lg * 8];
    const f32x4* muB = muT + ((long)(b * 13 + it) * 13) * 64 + lane;
    const f32x4* rsB = rsT + ((long)(b * 13 + it) * 13) * 64 + lane;

    float ez[13][4];
    float mx[4] = {-1e30f, -1e30f, -1e30f, -1e30f};
#pragma unroll
    for (int jt = 0; jt < 13; jt++) {
        int jr = min(jt * 16 + lrow, Nn - 1);
        half8 bf0 = *(const half8*)&Kp[(long)jr * 64 + lg * 8];
        half8 bf1 = *(const half8*)&Kp[(long)jr * 64 + 32 + lg * 8];
        f32x4 acc = {};
        acc = __builtin_amdgcn_mfma_f32_16x16x32_f16(af0, bf0, acc, 0, 0, 0);
        acc = __builtin_amdgcn_mfma_f32_16x16x32_f16(af1, bf1, acc, 0, 0, 0);
        f32x4 mu4 = muB[jt * 64];
        f32x4 rs4 = rsB[jt * 64];
        bool joob = (jt * 16 + lrow) > Nn - 1;
#pragma unroll
        for (int q = 0; q < 4; q++) {
            float z = (acc[q] - mu4[q]) * rs4[q];
            if (joob) z = -1e30f;
            ez[jt][q] = z;
            mx[q] = fmaxf(mx[q], z);
        }
    }
#pragma unroll
    for (int st = 1; st <= 8; st <<= 1)
#pragma unroll
        for (int q = 0; q < 4; q++) mx[q] = fmaxf(mx[q], __shfl_xor(mx[q], st));
    float sm[4] = {0.f, 0.f, 0.f, 0.f};
#pragma unroll
    for (int jt = 0; jt < 13; jt++)
#pragma unroll
        for (int q = 0; q < 4; q++) {
            float e = __expf(ez[jt][q] - mx[q]);
            ez[jt][q] = e;
            sm[q] += e;
        }
#pragma unroll
    for (int st = 1; st <= 8; st <<= 1)
#pragma unroll
        for (int q = 0; q < 4; q++) sm[q] += __shfl_xor(sm[q], st);
    float inv[4];
#pragma unroll
    for (int q = 0; q < 4; q++) inv[q] = 1.f / sm[q];
#pragma unroll
    for (int jt = 0; jt < 13; jt++)
#pragma unroll
        for (int q = 0; q < 4; q++)
            PB[lg * 4 + q][jt * 16 + lrow] = (half_t)(ez[jt][q] * inv[q]);
    __syncthreads();

    const half_t* Vtp = vt + ((long)bh * 64) * 224;
#pragma unroll
    for (int dt = 0; dt < 4; dt++) {
        f32x4 oacc = {};
#pragma unroll
        for (int kt = 0; kt < 7; kt++) {
            half8 pa = *(const half8*)&PB[lrow][kt * 32 + lg * 8];
            half8 vb = *(const half8*)&Vtp[(long)(dt * 16 + lrow) * 224 + kt * 32 + lg * 8];
            oacc = __builtin_amdgcn_mfma_f32_16x16x32_f16(pa, vb, oacc, 0, 0, 0);
        }
#pragma unroll
        for (int q = 0; q < 4; q++) {
            int i = i0 + lg * 4 + q;
            if (i < Nn)
                o[((long)(b * Nn) + i) * INNERc + h * 64 + dt * 16 + lrow] = (half_t)oacc[q];
        }
    }
}

// ---------------- host launcher ----------------
extern "C" void kernel_launch(void* const* d_in, const int* in_sizes, int n_in,
                              void* d_out, int out_size, void* d_ws, size_t ws_size,
                              hipStream_t stream) {
    const float* img     = (const float*)d_in[0];
    const float* patch_g = (const float*)d_in[2];
    const float* patch_b = (const float*)d_in[3];
    const float* W_patch = (const float*)d_in[4];
    const float* b_patch = (const float*)d_in[5];
    const float* emb_g   = (const float*)d_in[6];
    const float* emb_b   = (const float*)d_in[7];
    const float* pos     = (const float*)d_in[8];
    const float* cls     = (const float*)d_in[9];
    const float* ln_g    = (const float*)d_in[10];
    const float* ln_b    = (const float*)d_in[11];
    const float* W_qkv   = (const float*)d_in[12];
    const float* W_out   = (const float*)d_in[13];
    const float* b_out   = (const float*)d_in[14];
    const float* fin_g   = (const float*)d_in[15];
    const float* fin_b   = (const float*)d_in[16];
    const float* W_head  = (const float*)d_in[17];
    const float* b_head  = (const float*)d_in[18];
    float* out = (float*)d_out;

    const long SZ_XD  = (long)Bc * Nn * Dd;            // 4,841,472
    const long SZ_HD  = (long)Bc * NH * Nn * DHd;      // 4,841,472
    const long SZ_VT  = (long)Bc * NH * 64 * 224;      // 5,505,024
    const long SZ_TMP = (long)Bc * NPc * Dd;
    const long SZ_MU  = (long)Bc * 169 * 256 + 1024;   // fragment-layout stats

    float* x    = (float*)d_ws;
    float* tmp  = x + SZ_XD;
    float* muG  = tmp + SZ_TMP;
    float* rsG  = muG + SZ_MU;
    half_t* xh       = (half_t*)(rsG + SZ_MU);
    half_t* qhb      = xh + SZ_XD;
    half_t* khb      = qhb + SZ_HD;
    half_t* vtb      = khb + SZ_HD;
    half_t* clsh     = vtb + SZ_VT;                         // 32x768 f16
    half_t* wh_head  = clsh + 32 * Dd;                      // 1024x768 f16
    half_t* wt_patch = wh_head + 1024 * Dd;
    half_t* wt_qkv   = wt_patch + (long)Dd * Dd;
    half_t* wt_out   = wt_qkv + (long)DEPTHc * 3 * INNERc * Dd;

    // ---- weight prep ----
    hipLaunchKernelGGL(k_wprep, dim3(Dd / 32, Dd / 32, 1), dim3(32, 8), 0, stream,
                       W_patch, wt_patch, Dd, Dd);
    hipLaunchKernelGGL(k_wprep, dim3(3 * INNERc / 32, Dd / 32, DEPTHc), dim3(32, 8), 0, stream,
                       W_qkv, wt_qkv, Dd, 3 * INNERc);
    hipLaunchKernelGGL(k_wprep, dim3(Dd / 32, Dd / 32, DEPTHc), dim3(32, 8), 0, stream,
                       W_out, wt_out, Dd, Dd);
    hipLaunchKernelGGL(k_wprep_head, dim3(32, 24), dim3(32, 8), 0, stream,
                       W_head, wh_head);

    // 1. patchify + patch LN -> xh (f16)
    hipLaunchKernelGGL(k_patch_ln, dim3(Bc * NPc), dim3(256), 0, stream,
                       img, patch_g, patch_b, xh);
    // 2. patch GEMM (+b_patch) -> tmp fp32
    hipLaunchKernelGGL((k_hgemm<1, 0, float, 0>), dim3(6 * 49), dim3(256), 0, stream,
                       xh, wt_patch, b_patch, nullptr,
                       tmp, nullptr, nullptr, Bc * NPc, Dd, Dd);
    // 3. emb LN + cls concat + pos add -> x
    hipLaunchKernelGGL(k_embed, dim3(Bc * Nn), dim3(256), 0, stream,
                       tmp, cls, pos, emb_g, emb_b, x);

    const int Mrows = Bc * Nn;  // 6304
    for (int l = 0; l < DEPTHc; l++) {
        const float* g  = ln_g + (long)l * Dd;
        const float* bb = ln_b + (long)l * Dd;
        const half_t* Wq = wt_qkv + (long)l * 3 * INNERc * Dd;
        const half_t* Wo = wt_out + (long)l * Dd * Dd;
        const float* bo = b_out + (long)l * Dd;
        hipLaunchKernelGGL((k_ln<half_t>), dim3(Mrows), dim3(256), 0, stream,
                           x, g, bb, xh, (long)Dd, (long)Dd);
        // qkv GEMM; q/k head-major, V staged in LDS + written transposed coalesced
        hipLaunchKernelGGL((k_hgemm<0, 0, half_t, 1>), dim3(18 * 50), dim3(256), 0, stream,
                           xh, Wq, nullptr, nullptr,
                           qhb, khb, vtb, Mrows, 3 * INNERc, Dd);
        hipLaunchKernelGGL(k_stats, dim3(1352), dim3(256), 0, stream,
                           qhb, khb, (f32x4*)muG, (f32x4*)rsG);
        hipLaunchKernelGGL(k_attn2, dim3(4992), dim3(64), 0, stream,
                           qhb, khb, vtb, (const f32x4*)muG, (const f32x4*)rsG, xh);
        hipLaunchKernelGGL((k_hgemm<1, 1, float, 0>), dim3(6 * 50), dim3(256), 0, stream,
                           xh, Wo, bo, x,
                           x, nullptr, nullptr, Mrows, Dd, Dd);
    }
    // final LN (cls rows only) -> clsh f16
    hipLaunchKernelGGL((k_ln<half_t>), dim3(Bc), dim3(256), 0, stream,
                       x, fin_g, fin_b, clsh, (long)Nn * Dd, (long)Dd);
    // head GEMM: f16 dot per (row,col)
    hipLaunchKernelGGL(k_head, dim3(128), dim3(256), 0, stream,
                       clsh, wh_head, b_head, out);
}